// Round 1
// baseline (139.599 us; speedup 1.0000x reference)
//
#include <hip/hip_runtime.h>

#define AMBIENT 0.6f
#define DIFFUSE 0.8f

typedef float nfloat4 __attribute__((ext_vector_type(4)));

// Kernel 1: shaded4[p] = clip(features[p]*(AMBIENT+DIFFUSE*|n.l|),0,1) padded to 16B.
// ~4 MB of traffic, sub-µs; kept separate so the composite gather stays a single
// aligned dwordx4 from an L2-resident 1.6 MB table.
__global__ void shade_kernel(const float* __restrict__ features,
                             const float* __restrict__ normals,
                             const float* __restrict__ light_dir,
                             nfloat4* __restrict__ shaded, int P) {
    int p = blockIdx.x * blockDim.x + threadIdx.x;
    if (p >= P) return;
    float lx = light_dir[0], ly = light_dir[1], lz = light_dir[2];
    float inv = rsqrtf(lx * lx + ly * ly + lz * lz);
    lx *= inv; ly *= inv; lz *= inv;
    float nx = normals[3 * p + 0];
    float ny = normals[3 * p + 1];
    float nz = normals[3 * p + 2];
    float ndl = fabsf(nx * lx + ny * ly + nz * lz);
    float s = AMBIENT + DIFFUSE * ndl;
    nfloat4 c;
    c.x = fminf(fmaxf(features[3 * p + 0] * s, 0.0f), 1.0f);
    c.y = fminf(fmaxf(features[3 * p + 1] * s, 0.0f), 1.0f);
    c.z = fminf(fmaxf(features[3 * p + 2] * s, 0.0f), 1.0f);
    c.w = 0.0f;
    shaded[p] = c;
}

// Kernel 2: 1024 pixels / 256-thread block.
// Binary-weight alpha compositing == "first non-empty layer wins", and bg applies
// exactly when layer 0 is empty -> only idx[...,0] matters.
//
// v2: direct strided NT dword loads of the k=0 elements. Stride 40B < 64B line,
// so every idx line is fetched either way (same HBM bytes, same line-request
// count as the old full-tile dwordx4 stream), but this deletes the %5 extraction
// ALU, the lds_k0 staging array, and one __syncthreads. LDS is kept only for
// turning per-pixel float3 results into fully-coalesced float4 NT stores.
#define PX_PER_BLOCK 1024
__global__ __launch_bounds__(256) void composite_kernel(
        const int* __restrict__ idx,
        const nfloat4* __restrict__ shaded,
        nfloat4* __restrict__ out,
        int num_pixels) {
    __shared__ nfloat4 lds_c4[PX_PER_BLOCK * 3 / 4];      // 12 KB
    float* lds_c = (float*)lds_c4;

    const int K = 10;
    int base = blockIdx.x * PX_PER_BLOCK;
    int rem  = num_pixels - base;
    if (rem > PX_PER_BLOCK) rem = PX_PER_BLOCK;

    // Issue all 4 k=0 loads first (independent, NT: no reuse of idx lines).
    int i0[4];
#pragma unroll
    for (int j = 0; j < 4; ++j) {
        int lp = threadIdx.x + j * 256;
        i0[j] = (lp < rem)
                  ? __builtin_nontemporal_load(idx + (long long)(base + lp) * K)
                  : -1;
    }

    // Gather from the L2-resident shaded table (cached loads), stage to LDS.
    // lds_c stride-3 float writes: bank stride 3 over 64 lanes -> 2 lanes/bank, free.
#pragma unroll
    for (int j = 0; j < 4; ++j) {
        int lp = threadIdx.x + j * 256;
        nfloat4 c = {1.0f, 1.0f, 1.0f, 0.0f};            // background
        if (i0[j] >= 0) c = shaded[i0[j]];
        lds_c[lp * 3 + 0] = c.x;
        lds_c[lp * 3 + 1] = c.y;
        lds_c[lp * 3 + 2] = c.z;
    }
    __syncthreads();

    // Coalesced NT float4 stores of the packed float3 image.
    int n4 = (rem * 3) / 4;
    nfloat4* o = out + ((long long)base * 3) / 4;
    for (int i = threadIdx.x; i < n4; i += 256) {
        __builtin_nontemporal_store(lds_c4[i], &o[i]);
    }
    // Generic tail (never taken at N*H*W = 2^21: rem is always 1024).
    int nf = rem * 3;
    for (int i = n4 * 4 + threadIdx.x; i < nf; i += 256) {
        ((float*)o)[i] = lds_c[i];
    }
}

extern "C" void kernel_launch(void* const* d_in, const int* in_sizes, int n_in,
                              void* d_out, int out_size, void* d_ws, size_t ws_size,
                              hipStream_t stream) {
    const int*   idx       = (const int*)d_in[0];
    const float* features  = (const float*)d_in[1];
    const float* normals   = (const float*)d_in[2];
    const float* light_dir = (const float*)d_in[3];
    nfloat4*     out       = (nfloat4*)d_out;
    nfloat4*     shaded    = (nfloat4*)d_ws;

    const int P          = in_sizes[1] / 3;          // 100000
    const int num_pixels = out_size / 3;             // N*H*W = 2,097,152

    {
        int block = 256;
        int grid  = (P + block - 1) / block;
        shade_kernel<<<grid, block, 0, stream>>>(features, normals, light_dir, shaded, P);
    }
    {
        int block = 256;
        int grid  = (num_pixels + PX_PER_BLOCK - 1) / PX_PER_BLOCK;
        composite_kernel<<<grid, block, 0, stream>>>(idx, shaded, out, num_pixels);
    }
}